// Round 12
// baseline (356.873 us; speedup 1.0000x reference)
//
#include <hip/hip_runtime.h>

#define QLEN 2048
#define KVTOT 4096
#define DMODEL 1024
// log2(e)-domain constants: scores are pre-scaled by 0.125*log2(e)
#define MASKC2 -14427.0f   // -10000 * log2(e)
#define SENT2  -28854.0f

typedef __attribute__((ext_vector_type(8))) short bf16x8;
typedef __attribute__((ext_vector_type(4))) float f32x4;
typedef unsigned short u16;
typedef unsigned int u32;
typedef unsigned long long u64;

__device__ __forceinline__ u16 f2b(float f) {
  union { float f; unsigned u; } v; v.f = f;
  unsigned r = v.u + 0x7FFFu + ((v.u >> 16) & 1u);
  return (u16)(r >> 16);
}

__device__ __forceinline__ float b2f(u16 x) {
  union { u32 u; float f; } v; v.u = (u32)x << 16; return v.f;
}

__device__ __forceinline__ u32 cvt_pk_bf16(float lo, float hi) {
  u32 r;
  asm("v_cvt_pk_bf16_f32 %0, %1, %2" : "=v"(r) : "v"(lo), "v"(hi));
  return r;
}

__device__ __forceinline__ float exp2v(float x) {
  float r;
  asm("v_exp_f32 %0, %1" : "=v"(r) : "v"(x));
  return r;
}

__device__ __forceinline__ float max3f(float a, float b, float c) {
  float r;
  asm("v_max3_f32 %0, %1, %2, %3" : "=v"(r) : "v"(a), "v"(b), "v"(c));
  return r;
}

// async global->LDS, 16B per lane; lds dest = wave-uniform base + lane*16
__device__ __forceinline__ void gll16(const u16* g, u16* l) {
  __builtin_amdgcn_global_load_lds(
      (const __attribute__((address_space(1))) u32*)g,
      (__attribute__((address_space(3))) u32*)l, 16, 0, 0);
}

// ---------------------------------------------------------------------------
// past_k/past_v fp32 -> k_cat/v_cat rows 0..2047, plus kh bf16 head layout.
// ---------------------------------------------------------------------------
__global__ __launch_bounds__(256) void copy_past(
    const float* __restrict__ pk, const float* __restrict__ pv,
    float* __restrict__ kcat, float* __restrict__ vcat,
    u16* __restrict__ kh) {
  int i = blockIdx.x * 256 + threadIdx.x;        // float4 units
  int b = i >> 19;
  int r = i & 524287;
  size_t src = (size_t)i * 4;
  size_t dst = ((size_t)b * 1048576 + r) * 4;
  float4 kk = *(const float4*)&pk[src];
  float4 vv = *(const float4*)&pv[src];
  *(float4*)&kcat[dst] = kk;
  *(float4*)&vcat[dst] = vv;
  int s = r >> 8;
  int c4 = (r & 255) * 4;
  int h = c4 >> 6, d = c4 & 63;
  uint2 w = make_uint2(cvt_pk_bf16(kk.x, kk.y), cvt_pk_bf16(kk.z, kk.w));
  *(uint2*)&kh[((size_t)(b * 16 + h) * KVTOT + s) * 64 + d] = w;
}

// ---------------------------------------------------------------------------
// mask int32 (B,Q,4096) -> bits u64 (B,Q,64)
// ---------------------------------------------------------------------------
__global__ __launch_bounds__(256) void maskpack(
    const int* __restrict__ mask, u64* __restrict__ bits) {
  int w = blockIdx.x * 4 + (threadIdx.x >> 6);
  int lane = threadIdx.x & 63;
  int mv = mask[(size_t)w * 64 + lane];
  u64 b = __ballot(mv != 0);
  if (lane == 0) bits[w] = b;
}

// ---------------------------------------------------------------------------
// Weights fp32 -> bf16, 4 matrices of 1M elems (blockIdx.y selects)
// ---------------------------------------------------------------------------
__global__ __launch_bounds__(256) void w2b(
    const float* __restrict__ w0, const float* __restrict__ w1,
    const float* __restrict__ w2, const float* __restrict__ w3,
    u16* __restrict__ dst) {
  const float* src = blockIdx.y == 0 ? w0 : blockIdx.y == 1 ? w1
                   : blockIdx.y == 2 ? w2 : w3;
  size_t i = ((size_t)blockIdx.x * 256 + threadIdx.x) * 8;
  float4 a = *(const float4*)&src[i];
  float4 b = *(const float4*)&src[i + 4];
  uint4 o = {cvt_pk_bf16(a.x, a.y), cvt_pk_bf16(a.z, a.w),
             cvt_pk_bf16(b.x, b.y), cvt_pk_bf16(b.z, b.w)};
  *(uint4*)&dst[(size_t)blockIdx.y * 1048576 + i] = o;
}

// ---------------------------------------------------------------------------
// Activations fp32 -> bf16 (4.19M elems each); dst0 for y==0, dst12 for y=1,2
// ---------------------------------------------------------------------------
__global__ __launch_bounds__(256) void a2b(
    const float* __restrict__ a0, const float* __restrict__ a1,
    const float* __restrict__ a2, u16* __restrict__ dst0,
    u16* __restrict__ dst12) {
  const int y = blockIdx.y;
  const float* src = y == 0 ? a0 : y == 1 ? a1 : a2;
  u16* dst = y == 0 ? dst0 : dst12 + (size_t)(y - 1) * 4194304;
  size_t i = ((size_t)blockIdx.x * 256 + threadIdx.x) * 8;
  float4 a = *(const float4*)&src[i];
  float4 b = *(const float4*)&src[i + 4];
  uint4 o = {cvt_pk_bf16(a.x, a.y), cvt_pk_bf16(a.z, a.w),
             cvt_pk_bf16(b.x, b.y), cvt_pk_bf16(b.z, b.w)};
  *(uint4*)&dst[i] = o;
}

// ---------------------------------------------------------------------------
// z-fused QKV projections: C = A*W^T + bias. BOTH sides bf16 via
// global_load_lds. grid (8,32,3). A: z==0 -> Ab0, z>=1 -> Ab12+(z-1)*4M.
// ---------------------------------------------------------------------------
__global__ __launch_bounds__(256) void gemm_qkv(
    const u16* __restrict__ Ab0, const u16* __restrict__ Ab12,
    const u16* __restrict__ Wb,
    const float* __restrict__ bq, const float* __restrict__ bk,
    const float* __restrict__ bv,
    u16* __restrict__ qh, float* __restrict__ kcat, u16* __restrict__ kh,
    float* __restrict__ vcat) {
  const int K = 1024, N = 1024;
  __shared__ u16 As[128][32];
  __shared__ u16 Bs[128][32];
  const int z = blockIdx.z;
  const u16* A = (z == 0) ? Ab0 : Ab12 + (size_t)(z - 1) * 4194304;
  const u16* W = Wb + (size_t)z * 1048576;
  const float* bias = (z == 0) ? bq : (z == 1) ? bk : bv;
  const int t = threadIdx.x;
  const int m0 = blockIdx.y * 128, n0 = blockIdx.x * 128;
  const int lane = t & 63, wid = t >> 6;
  const int wr = (wid >> 1) * 64, wc = (wid & 1) * 64;
  const int lr = lane & 15, lg = lane >> 4;
  const int ko = lg * 8;

  f32x4 acc[4][4];
  #pragma unroll
  for (int m = 0; m < 4; ++m)
    #pragma unroll
    for (int n = 0; n < 4; ++n)
      acc[m][n] = (f32x4){0.f, 0.f, 0.f, 0.f};

  for (int k0 = 0; k0 < K; k0 += 32) {
    __syncthreads();
    #pragma unroll
    for (int j = 0; j < 2; ++j) {
      int idx = t + j * 256;
      int r = idx >> 2, c8 = (idx & 3) * 8;
      size_t ldsoff = (size_t)(j * 256 + (t & ~63)) * 8;
      gll16(A + (size_t)(m0 + r) * K + k0 + c8, &As[0][0] + ldsoff);
      gll16(W + (size_t)(n0 + r) * K + k0 + c8, &Bs[0][0] + ldsoff);
    }
    __syncthreads();
    bf16x8 av[4], bv4[4];
    #pragma unroll
    for (int m = 0; m < 4; ++m)
      av[m] = *(const bf16x8*)&As[wr + m * 16 + lr][ko];
    #pragma unroll
    for (int n = 0; n < 4; ++n)
      bv4[n] = *(const bf16x8*)&Bs[wc + n * 16 + lr][ko];
    #pragma unroll
    for (int m = 0; m < 4; ++m)
      #pragma unroll
      for (int n = 0; n < 4; ++n)
        acc[m][n] = __builtin_amdgcn_mfma_f32_16x16x32_bf16(av[m], bv4[n], acc[m][n], 0, 0, 0);
  }

  const int rq = lg * 4;
  #pragma unroll
  for (int m = 0; m < 4; ++m) {
    #pragma unroll
    for (int r = 0; r < 4; ++r) {
      int row = m0 + wr + m * 16 + rq + r;     // = b*2048 + s
      int bb = row >> 11, s = row & 2047;
      #pragma unroll
      for (int n = 0; n < 4; ++n) {
        int col = n0 + wc + n * 16 + lr;
        float val = acc[m][n][r] + bias[col];
        int hh = col >> 6, d = col & 63;
        if (z == 0) {
          // scale by 1/8 * log2(e): scores live in exp2 domain
          qh[((size_t)(bb * 16 + hh) * QLEN + s) * 64 + d] = f2b(val * 0.18033688f);
        } else if (z == 1) {
          kcat[(size_t)(bb * 4096 + 2048 + s) * 1024 + col] = val;
          kh[((size_t)(bb * 16 + hh) * KVTOT + 2048 + s) * 64 + d] = f2b(val);
        } else {
          vcat[(size_t)(bb * 4096 + 2048 + s) * 1024 + col] = val;
        }
      }
    }
  }
}

// ---------------------------------------------------------------------------
// Final GEMM: A bf16 (attn out), W bf16 — both via global_load_lds.
// ---------------------------------------------------------------------------
__global__ __launch_bounds__(256) void gemm_out(
    const u16* __restrict__ A, const u16* __restrict__ W,
    const float* __restrict__ bias, float* __restrict__ C) {
  const int K = 1024, N = 1024;
  __shared__ u16 As[128][32];
  __shared__ u16 Bs[128][32];
  const int t = threadIdx.x;
  const int m0 = blockIdx.y * 128, n0 = blockIdx.x * 128;
  const int lane = t & 63, wid = t >> 6;
  const int wr = (wid >> 1) * 64, wc = (wid & 1) * 64;
  const int lr = lane & 15, lg = lane >> 4;
  const int ko = lg * 8;

  f32x4 acc[4][4];
  #pragma unroll
  for (int m = 0; m < 4; ++m)
    #pragma unroll
    for (int n = 0; n < 4; ++n)
      acc[m][n] = (f32x4){0.f, 0.f, 0.f, 0.f};

  for (int k0 = 0; k0 < K; k0 += 32) {
    __syncthreads();
    #pragma unroll
    for (int j = 0; j < 2; ++j) {
      int idx = t + j * 256;
      int r = idx >> 2, c8 = (idx & 3) * 8;
      size_t ldsoff = (size_t)(j * 256 + (t & ~63)) * 8;
      gll16(A + (size_t)(m0 + r) * K + k0 + c8, &As[0][0] + ldsoff);
      gll16(W + (size_t)(n0 + r) * K + k0 + c8, &Bs[0][0] + ldsoff);
    }
    __syncthreads();
    bf16x8 av[4], bv4[4];
    #pragma unroll
    for (int m = 0; m < 4; ++m)
      av[m] = *(const bf16x8*)&As[wr + m * 16 + lr][ko];
    #pragma unroll
    for (int n = 0; n < 4; ++n)
      bv4[n] = *(const bf16x8*)&Bs[wc + n * 16 + lr][ko];
    #pragma unroll
    for (int m = 0; m < 4; ++m)
      #pragma unroll
      for (int n = 0; n < 4; ++n)
        acc[m][n] = __builtin_amdgcn_mfma_f32_16x16x32_bf16(av[m], bv4[n], acc[m][n], 0, 0, 0);
  }

  const int rq = lg * 4;
  #pragma unroll
  for (int m = 0; m < 4; ++m) {
    #pragma unroll
    for (int r = 0; r < 4; ++r) {
      int row = m0 + wr + m * 16 + rq + r;
      float* cp = C + (size_t)row * N;
      #pragma unroll
      for (int n = 0; n < 4; ++n) {
        int col = n0 + wc + n * 16 + lr;
        cp[col] = acc[m][n][r] + bias[col];
      }
    }
  }
}

// ---------------------------------------------------------------------------
// vcat fp32 [B][4096][1024] -> bf16 transposed [B][16][64][4096]
// ---------------------------------------------------------------------------
__global__ __launch_bounds__(256) void repack_vt(
    const float* __restrict__ src, u16* __restrict__ dst) {
  __shared__ u16 T[64][72];
  const int t = threadIdx.x;
  const int kv0 = blockIdx.x * 64;
  const int bh = blockIdx.y;
  const int b = bh >> 4, h = bh & 15;
  #pragma unroll
  for (int it = 0; it < 4; ++it) {
    int idx = t + it * 256;
    int r = idx >> 4;
    int c4 = (idx & 15) * 4;
    float4 v = *(const float4*)(src + (size_t)(b * KVTOT + kv0 + r) * DMODEL + h * 64 + c4);
    *(uint2*)&T[r][c4] = make_uint2(cvt_pk_bf16(v.x, v.y), cvt_pk_bf16(v.z, v.w));
  }
  __syncthreads();
  #pragma unroll
  for (int it = 0; it < 2; ++it) {
    int idx = t + it * 256;
    int d = idx & 63;
    int kc8 = (idx >> 6) * 8;
    bf16x8 o;
    #pragma unroll
    for (int j = 0; j < 8; ++j) o[j] = (short)T[kc8 + j][d];
    *(bf16x8*)(dst + (size_t)((b * 16 + h) * 64 + d) * KVTOT + kv0 + kc8) = o;
  }
}

// ---------------------------------------------------------------------------
// MFMA flash attention v12 (= v10 + deep prefetch): flash-decode, 4 waves
// split KV (1024 each), K/V/mask ALL prefetched one full iteration ahead in
// registers (macro buffer rotation, no runtime-indexed arrays).
// ---------------------------------------------------------------------------
__global__ __launch_bounds__(256, 2) void attn_mfma(
    const u16* __restrict__ qh, const u16* __restrict__ kh,
    const u16* __restrict__ vt, const u64* __restrict__ mbits,
    u16* __restrict__ out) {
  // shm dual-role (barrier-separated):
  //  loop phase : per-wave P dbuf at shm + wid*2304  (2 x [16][72] u16)
  //  merge phase: bf16 O-partials    shm + w*4608    ([64][72] u16)
  __shared__ __align__(16) u16 shm[4 * 64 * 72];
  __shared__ float mM[4][64];
  __shared__ float mL[4][64];
  const int t = threadIdx.x;
  const int wid = t >> 6, lane = t & 63;
  const int lr = lane & 15, lg = lane >> 4;
  const int fid = blockIdx.x;                      // 0..1023
  const int virt = (fid & 7) * 128 + (fid >> 3);   // XCD-chunked: 4 bh per XCD
  const int bh = virt >> 5, qt = virt & 31;
  const int b = bh >> 4, h = bh & 15;
  const int q0 = qt * 64;

  u16* bufA = shm + wid * 2304;                    // wave-private [16][72]
  u16* bufB = bufA + 1152;

  bf16x8 ones;
  #pragma unroll
  for (int j = 0; j < 8; ++j) ones[j] = (short)0x3F80;

  // Q fragments (B-operand: col=q=lr, k=d=lg*8+j), 4 q-frags = 64 q rows
  bf16x8 qf[4][2];
  #pragma unroll
  for (int i = 0; i < 4; ++i) {
    const u16* qp = qh + ((size_t)bh * QLEN + q0 + i * 16 + lr) * 64 + lg * 8;
    qf[i][0] = *(const bf16x8*)qp;
    qf[i][1] = *(const bf16x8*)(qp + 32);
  }

  // this wave's private kv window: [wid*1024, wid*1024+1024)
  const u16* kbase = kh + (size_t)bh * KVTOT * 64 + (size_t)wid * 1024 * 64;
  const u16* vbase = vt + (size_t)bh * 64 * KVTOT + wid * 1024;
  const u64* mbase = mbits + ((size_t)b * QLEN + q0 + lr) * 64 + wid * 16;

  float mprev[4] = {SENT2, SENT2, SENT2, SENT2};
  f32x4 oacc[4][4];
  f32x4 oaccL[4];
  #pragma unroll
  for (int i = 0; i < 4; ++i) {
    oaccL[i] = (f32x4){0.f, 0.f, 0.f, 0.f};
    #pragma unroll
    for (int dt = 0; dt < 4; ++dt) oacc[i][dt] = (f32x4){0.f, 0.f, 0.f, 0.f};
  }

  // preload K fragments for tile 0 (A-operand: row=kv=tile*16+lr, k=d)
  bf16x8 kf[4][2];
  #pragma unroll
  for (int tile = 0; tile < 4; ++tile) {
    const u16* kp = kbase + (size_t)(tile * 16 + lr) * 64 + lg * 8;
    kf[tile][0] = *(const bf16x8*)kp;
    kf[tile][1] = *(const bf16x8*)(kp + 32);
  }

  // ---- pipeline stages (i is a literal at every call site -> constant-folds)
  auto QK = [&](int i, f32x4* sacc, u64 mb) {
    u64 mq = mb >> (lg * 4);
    const float negm = -mprev[i], negmm = MASKC2 - mprev[i];
    #pragma unroll
    for (int tile = 0; tile < 4; ++tile) {
      unsigned nib = (unsigned)((mq >> (tile * 16)) & 0xFull);
      #pragma unroll
      for (int r = 0; r < 4; ++r)
        sacc[tile][r] = (nib & (1u << r)) ? negmm : negm;
    }
    __builtin_amdgcn_s_setprio(1);
    #pragma unroll
    for (int tile = 0; tile < 4; ++tile) {
      sacc[tile] = __builtin_amdgcn_mfma_f32_16x16x32_bf16(kf[tile][0], qf[i][0], sacc[tile], 0, 0, 0);
      sacc[tile] = __builtin_amdgcn_mfma_f32_16x16x32_bf16(kf[tile][1], qf[i][1], sacc[tile], 0, 0, 0);
    }
    __builtin_amdgcn_s_setprio(0);
  };

  auto SM = [&](int i, f32x4* sacc, u16* pbuf) {
    // per-lane local max; __all over 64 lanes covers the whole 16q x 64kv tile
    float t1 = max3f(sacc[0][0], sacc[0][1], sacc[0][2]);
    float t2 = max3f(sacc[0][3], sacc[1][0], sacc[1][1]);
    float t3 = max3f(sacc[1][2], sacc[1][3], sacc[2][0]);
    float t4 = max3f(sacc[2][1], sacc[2][2], sacc[2][3]);
    float t5 = max3f(sacc[3][0], sacc[3][1], sacc[3][2]);
    float lmax = fmaxf(sacc[3][3], t1);
    lmax = max3f(lmax, t2, t3);
    lmax = max3f(lmax, t4, t5);
    if (!__all(lmax <= 11.0f)) {         // rare: rescale path
      float rmax = fmaxf(lmax, __shfl_xor(lmax, 16));
      rmax = fmaxf(rmax, __shfl_xor(rmax, 32));
      float shift = fmaxf(rmax, 0.f);
      float corr = exp2v(-shift);
      float cr[4];
      #pragma unroll
      for (int r = 0; r < 4; ++r) cr[r] = __shfl(corr, lg * 4 + r);
      #pragma unroll
      for (int dt = 0; dt < 4; ++dt)
        #pragma unroll
        for (int r = 0; r < 4; ++r) oacc[i][dt][r] *= cr[r];
      #pragma unroll
      for (int r = 0; r < 4; ++r) oaccL[i][r] *= cr[r];
      mprev[i] += shift;
      #pragma unroll
      for (int tile = 0; tile < 4; ++tile)
        #pragma unroll
        for (int r = 0; r < 4; ++r) sacc[tile][r] -= shift;
    }
    #pragma unroll
    for (int tile = 0; tile < 4; ++tile) {
      float p0 = exp2v(sacc[tile][0]);
      float p1 = exp2v(sacc[tile][1]);
      float p2 = exp2v(sacc[tile][2]);
      float p3 = exp2v(sacc[tile][3]);
      *(uint2*)&pbuf[lr * 72 + tile * 16 + lg * 4] =
          make_uint2(cvt_pk_bf16(p0, p1), cvt_pk_bf16(p2, p3));
    }
  };

  f32x4 sA[4], sB[4];

  // V + mask double buffers (register resident, rotated by macro)
  bf16x8 vf0[4][2], vf1[4][2];
  u64 mb0[4], mb1[4];

  // prologue: load iter-0 V and mask
  #pragma unroll
  for (int i = 0; i < 4; ++i) mb0[i] = mbase[(size_t)i * 1024];
  #pragma unroll
  for (int dt = 0; dt < 4; ++dt) {
    const u16* vq = vbase + (size_t)(dt * 16 + lr) * KVTOT + lg * 8;
    vf0[dt][0] = *(const bf16x8*)vq;
    vf0[dt][1] = *(const bf16x8*)(vq + 32);
  }

#define PV_M(i, pbuf, VV)                                                      \
  {                                                                            \
    bf16x8 pa0 = *(const bf16x8*)&pbuf[lr * 72 + lg * 8];                      \
    bf16x8 pa1 = *(const bf16x8*)&pbuf[lr * 72 + 32 + lg * 8];                 \
    __builtin_amdgcn_s_setprio(1);                                             \
    _Pragma("unroll")                                                          \
    for (int dt = 0; dt < 4; ++dt) {                                           \
      oacc[i][dt] = __builtin_amdgcn_mfma_f32_16x16x32_bf16(pa0, VV[dt][0], oacc[i][dt], 0, 0, 0); \
      oacc[i][dt] = __builtin_amdgcn_mfma_f32_16x16x32_bf16(pa1, VV[dt][1], oacc[i][dt], 0, 0, 0); \
    }                                                                          \
    oaccL[i] = __builtin_amdgcn_mfma_f32_16x16x32_bf16(pa0, ones, oaccL[i], 0, 0, 0); \
    oaccL[i] = __builtin_amdgcn_mfma_f32_16x16x32_bf16(pa1, ones, oaccL[i], 0, 0, 0); \
    __builtin_amdgcn_s_setprio(0);                                             \
  }

#define ITER_M(IT, VCUR, VNXT, MCUR, MNXT)                                     \
  {                                                                            \
    const int it_ = (IT);                                                      \
    if (it_ + 1 < 16) {                                                        \
      /* prefetch next iter's mask + V a FULL iteration ahead */               \
      _Pragma("unroll")                                                        \
      for (int i = 0; i < 4; ++i) MNXT[i] = mbase[(size_t)i * 1024 + it_ + 1]; \
      const u16* vp_ = vbase + (it_ + 1) * 64;                                 \
      _Pragma("unroll")                                                        \
      for (int dt = 0; dt < 4; ++dt) {                                         \
        const u16* vq_ = vp_ + (size_t)(dt * 16 + lr) * KVTOT + lg * 8;        \
        VNXT[dt][0] = *(const bf16x8*)vq_;                                     \
        VNXT[dt][1] = *(const bf16x8*)(vq_ + 32);                              \
      }                                                                        \
    }                                                                          \
    QK(0, sA, MCUR[0]);                                                        \
    SM(0, sA, bufA);                                                           \
    QK(1, sB, MCUR[1]);                                                        \
    PV_M(0, bufA, VCUR);                                                       \
    SM(1, sB, bufB);                                                           \
    QK(2, sA, MCUR[2]);                                                        \
    PV_M(1, bufB, VCUR);                                                       \
    SM(2, sA, bufA);                                                           \
    QK(3, sB, MCUR[3]);                                                        \
    if (it_ + 1 < 16) {                                                        \
      const u16* kp_ = kbase + (size_t)(it_ + 1) * 4096;                       \
      _Pragma("unroll")                                                        \
      for (int tile = 0; tile < 4; ++tile) {                                   \
        const u16* kq_ = kp_ + (size_t)(tile * 16 + lr) * 64 + lg * 8;         \
        kf[tile][0] = *(const bf16x8*)kq_;                                     \
        kf[tile][1] = *(const bf16x8*)(kq_ + 32);                              \
      }                                                                        \
    }                                                                          \
    PV_M(2, bufA, VCUR);                                                       \
    SM(3, sB, bufB);                                                           \
    PV_M(3, bufB, VCUR);                                                       \
  }

  for (int ii = 0; ii < 8; ++ii) {
    ITER_M(2 * ii,     vf0, vf1, mb0, mb1);
    ITER_M(2 * ii + 1, vf1, vf0, mb1, mb0);
  }
#undef ITER_M
#undef PV_M

  // ---- merge the 4 kv-partials; staging overlays P buffers -> barrier first
  __syncthreads();
  u16* mo = shm + wid * 4608;                      // [64][72] bf16
  #pragma unroll
  for (int i = 0; i < 4; ++i)
    #pragma unroll
    for (int dt = 0; dt < 4; ++dt)
      #pragma unroll
      for (int r = 0; r < 4; ++r)
        mo[(i * 16 + lg * 4 + r) * 72 + dt * 16 + lr] = f2b(oacc[i][dt][r]);
  if (lr == 0) {
    #pragma unroll
    for (int i = 0; i < 4; ++i)
      #pragma unroll
      for (int r = 0; r < 4; ++r)
        mL[wid][i * 16 + lg * 4 + r] = oaccL[i][r];
  }
  if (lg == 0) {
    #pragma unroll
    for (int i = 0; i < 4; ++i) mM[wid][i * 16 + lr] = mprev[i];
  }
  __syncthreads();

  // wave `wid` merges q-rows [wid*16, wid*16+16); lane: q=lr, d=lg*16..+15
  const int q = wid * 16 + lr;
  float m0 = mM[0][q], m1 = mM[1][q], m2 = mM[2][q], m3 = mM[3][q];
  float mm = fmaxf(max3f(m0, m1, m2), m3);
  float w0 = exp2v(m0 - mm), w1 = exp2v(m1 - mm);
  float w2 = exp2v(m2 - mm), w3 = exp2v(m3 - mm);
  float l = mL[0][q] * w0 + mL[1][q] * w1 + mL[2][q] * w2 + mL[3][q] * w3;
  float inv = 1.f / l;
  float wgt[4] = {w0 * inv, w1 * inv, w2 * inv, w3 * inv};
  float o[16];
  #pragma unroll
  for (int j = 0; j < 16; ++j) o[j] = 0.f;
  #pragma unroll
  for (int w = 0; w < 4; ++w) {
    const u16* src = shm + w * 4608 + q * 72 + lg * 16;
    bf16x8 a0 = *(const bf16x8*)src;
    bf16x8 a1 = *(const bf16x8*)(src + 8);
    #pragma unroll
    for (int j = 0; j < 8; ++j) {
      o[j]     += b2f((u16)a0[j]) * wgt[w];
      o[8 + j] += b2f((u16)a1[j]) * wgt[w];
    }
  }
  u16* op = out + ((size_t)b * QLEN + q0 + q) * DMODEL + h * 64 + lg * 16;
  uint4 wA = {cvt_pk_bf16(o[0], o[1]), cvt_pk_bf16(o[2], o[3]),
              cvt_pk_bf16(o[4], o[5]), cvt_pk_bf16(o[6], o[7])};
  uint4 wB = {cvt_pk_bf16(o[8], o[9]), cvt_pk_bf16(o[10], o[11]),
              cvt_pk_bf16(o[12], o[13]), cvt_pk_bf16(o[14], o[15])};
  *(uint4*)op = wA;
  *(uint4*)(op + 8) = wB;
}

// ---------------------------------------------------------------------------
extern "C" void kernel_launch(void* const* d_in, const int* in_sizes, int n_in,
                              void* d_out, int out_size, void* d_ws, size_t ws_size,
                              hipStream_t stream) {
  const float* q      = (const float*)d_in[0];
  const float* k      = (const float*)d_in[1];
  const float* v      = (const float*)d_in[2];
  const float* past_k = (const float*)d_in[3];
  const float* past_v = (const float*)d_in[4];
  const int*   mask   = (const int*)d_in[5];
  const float* Wq     = (const float*)d_in[6];
  const float* bq     = (const float*)d_in[7];
  const float* Wk     = (const float*)d_in[8];
  const float* bk     = (const float*)d_in[9];
  const float* Wv     = (const float*)d_in[10];
  const float* bv     = (const float*)d_in[11];
  const float* Wl     = (const float*)d_in[12];
  const float* bl     = (const float*)d_in[13];

  float* xout = (float*)d_out;                    // (B, Q, D)
  float* kcat = xout + 4194304;                   // (B, 4096, D)
  float* vcat = xout + 12582912;

  // ws (u16 units): attno 0..4M | qh 4..8M | kh 8..16M | vt 16..24M |
  //                 Wb 24..28M | mbits after (2MB)
  // ab bf16 activations OVERLAY [attno | vt] (consumed before those are written)
  u16* wsb = (u16*)d_ws;
  u16* attno = wsb;
  u16* qh = wsb + 4194304;
  u16* kh = wsb + 8388608;
  u16* vt = wsb + 16777216;
  u16* Wb = wsb + 25165824;
  u64* mbits = (u64*)(wsb + 29360128);

  copy_past<<<4096, 256, 0, stream>>>(past_k, past_v, kcat, vcat, kh);
  maskpack<<<65536, 256, 0, stream>>>(mask, mbits);
  w2b<<<dim3(512, 4), 256, 0, stream>>>(Wq, Wk, Wv, Wl, Wb);
  a2b<<<dim3(2048, 3), 256, 0, stream>>>(q, k, v, attno, vt);

  gemm_qkv<<<dim3(8, 32, 3), 256, 0, stream>>>(
      attno, vt, Wb, bq, bk, bv, qh, kcat, kh, vcat);

  repack_vt<<<dim3(64, 32), 256, 0, stream>>>(vcat, vt);

  attn_mfma<<<1024, 256, 0, stream>>>(qh, kh, vt, mbits, attno);

  gemm_out<<<dim3(8, 32), 256, 0, stream>>>(attno, Wb + 3145728, bl, xout);
}

// Round 13
// 295.449 us; speedup vs baseline: 1.2079x; 1.2079x over previous
//
#include <hip/hip_runtime.h>

#define QLEN 2048
#define KVTOT 4096
#define DMODEL 1024
// log2(e)-domain constants: scores are pre-scaled by 0.125*log2(e)
#define MASKC2 -14427.0f   // -10000 * log2(e)
#define SENT2  -28854.0f

typedef __attribute__((ext_vector_type(8))) short bf16x8;
typedef __attribute__((ext_vector_type(4))) float f32x4;
typedef unsigned short u16;
typedef unsigned int u32;
typedef unsigned long long u64;

__device__ __forceinline__ u16 f2b(float f) {
  union { float f; unsigned u; } v; v.f = f;
  unsigned r = v.u + 0x7FFFu + ((v.u >> 16) & 1u);
  return (u16)(r >> 16);
}

__device__ __forceinline__ float b2f(u16 x) {
  union { u32 u; float f; } v; v.u = (u32)x << 16; return v.f;
}

__device__ __forceinline__ u32 cvt_pk_bf16(float lo, float hi) {
  u32 r;
  asm("v_cvt_pk_bf16_f32 %0, %1, %2" : "=v"(r) : "v"(lo), "v"(hi));
  return r;
}

__device__ __forceinline__ float exp2v(float x) {
  float r;
  asm("v_exp_f32 %0, %1" : "=v"(r) : "v"(x));
  return r;
}

__device__ __forceinline__ float max3f(float a, float b, float c) {
  float r;
  asm("v_max3_f32 %0, %1, %2, %3" : "=v"(r) : "v"(a), "v"(b), "v"(c));
  return r;
}

// async global->LDS, 16B per lane; lds dest = wave-uniform base + lane*16
__device__ __forceinline__ void gll16(const u16* g, u16* l) {
  __builtin_amdgcn_global_load_lds(
      (const __attribute__((address_space(1))) u32*)g,
      (__attribute__((address_space(3))) u32*)l, 16, 0, 0);
}

// ---------------------------------------------------------------------------
// Fused elementwise prep (one dispatch, blockIdx ranges):
//  [0,4096)      : past_k/past_v -> k_cat/v_cat + kh bf16
//  [4096,6144)   : weights fp32 -> bf16 (4 matrices)
//  [6144,12288)  : activations q/k/v fp32 -> bf16
// ---------------------------------------------------------------------------
__global__ __launch_bounds__(256) void prep(
    const float* __restrict__ pk, const float* __restrict__ pv,
    float* __restrict__ kcat, float* __restrict__ vcat,
    u16* __restrict__ kh,
    const float* __restrict__ w0, const float* __restrict__ w1,
    const float* __restrict__ w2, const float* __restrict__ w3,
    u16* __restrict__ wdst,
    const float* __restrict__ aq, const float* __restrict__ ak,
    const float* __restrict__ av, u16* __restrict__ adst0,
    u16* __restrict__ adst12) {
  const int bid = blockIdx.x;
  if (bid < 4096) {
    int i = bid * 256 + threadIdx.x;             // float4 units
    int b = i >> 19;
    int r = i & 524287;
    size_t src = (size_t)i * 4;
    size_t dst = ((size_t)b * 1048576 + r) * 4;
    float4 kk = *(const float4*)&pk[src];
    float4 vv = *(const float4*)&pv[src];
    *(float4*)&kcat[dst] = kk;
    *(float4*)&vcat[dst] = vv;
    int s = r >> 8;
    int c4 = (r & 255) * 4;
    int h = c4 >> 6, d = c4 & 63;
    uint2 w = make_uint2(cvt_pk_bf16(kk.x, kk.y), cvt_pk_bf16(kk.z, kk.w));
    *(uint2*)&kh[((size_t)(b * 16 + h) * KVTOT + s) * 64 + d] = w;
  } else if (bid < 6144) {
    int t2 = bid - 4096;
    int y = t2 >> 9, x = t2 & 511;
    const float* src = y == 0 ? w0 : y == 1 ? w1 : y == 2 ? w2 : w3;
    size_t i = ((size_t)x * 256 + threadIdx.x) * 8;
    float4 a = *(const float4*)&src[i];
    float4 b = *(const float4*)&src[i + 4];
    uint4 o = {cvt_pk_bf16(a.x, a.y), cvt_pk_bf16(a.z, a.w),
               cvt_pk_bf16(b.x, b.y), cvt_pk_bf16(b.z, b.w)};
    *(uint4*)&wdst[(size_t)y * 1048576 + i] = o;
  } else {
    int t3 = bid - 6144;
    int y = t3 >> 11, x = t3 & 2047;
    const float* src = y == 0 ? aq : y == 1 ? ak : av;
    u16* dst = y == 0 ? adst0 : adst12 + (size_t)(y - 1) * 4194304;
    size_t i = ((size_t)x * 256 + threadIdx.x) * 8;
    float4 a = *(const float4*)&src[i];
    float4 b = *(const float4*)&src[i + 4];
    uint4 o = {cvt_pk_bf16(a.x, a.y), cvt_pk_bf16(a.z, a.w),
               cvt_pk_bf16(b.x, b.y), cvt_pk_bf16(b.z, b.w)};
    *(uint4*)&dst[i] = o;
  }
}

// ---------------------------------------------------------------------------
// mask int32 (B,Q,4096) -> bits u64 (B,Q,64)
// ---------------------------------------------------------------------------
__global__ __launch_bounds__(256) void maskpack(
    const int* __restrict__ mask, u64* __restrict__ bits) {
  int w = blockIdx.x * 4 + (threadIdx.x >> 6);
  int lane = threadIdx.x & 63;
  int mv = mask[(size_t)w * 64 + lane];
  u64 b = __ballot(mv != 0);
  if (lane == 0) bits[w] = b;
}

// ---------------------------------------------------------------------------
// z-fused QKV projections: C = A*W^T + bias. BOTH sides bf16 via
// global_load_lds. grid (8,32,3). A: z==0 -> Ab0, z>=1 -> Ab12+(z-1)*4M.
// ---------------------------------------------------------------------------
__global__ __launch_bounds__(256) void gemm_qkv(
    const u16* __restrict__ Ab0, const u16* __restrict__ Ab12,
    const u16* __restrict__ Wb,
    const float* __restrict__ bq, const float* __restrict__ bk,
    const float* __restrict__ bv,
    u16* __restrict__ qh, float* __restrict__ kcat, u16* __restrict__ kh,
    float* __restrict__ vcat) {
  const int K = 1024, N = 1024;
  __shared__ u16 As[128][32];
  __shared__ u16 Bs[128][32];
  const int z = blockIdx.z;
  const u16* A = (z == 0) ? Ab0 : Ab12 + (size_t)(z - 1) * 4194304;
  const u16* W = Wb + (size_t)z * 1048576;
  const float* bias = (z == 0) ? bq : (z == 1) ? bk : bv;
  const int t = threadIdx.x;
  const int m0 = blockIdx.y * 128, n0 = blockIdx.x * 128;
  const int lane = t & 63, wid = t >> 6;
  const int wr = (wid >> 1) * 64, wc = (wid & 1) * 64;
  const int lr = lane & 15, lg = lane >> 4;
  const int ko = lg * 8;

  f32x4 acc[4][4];
  #pragma unroll
  for (int m = 0; m < 4; ++m)
    #pragma unroll
    for (int n = 0; n < 4; ++n)
      acc[m][n] = (f32x4){0.f, 0.f, 0.f, 0.f};

  for (int k0 = 0; k0 < K; k0 += 32) {
    __syncthreads();
    #pragma unroll
    for (int j = 0; j < 2; ++j) {
      int idx = t + j * 256;
      int r = idx >> 2, c8 = (idx & 3) * 8;
      size_t ldsoff = (size_t)(j * 256 + (t & ~63)) * 8;
      gll16(A + (size_t)(m0 + r) * K + k0 + c8, &As[0][0] + ldsoff);
      gll16(W + (size_t)(n0 + r) * K + k0 + c8, &Bs[0][0] + ldsoff);
    }
    __syncthreads();
    bf16x8 av4[4], bv4[4];
    #pragma unroll
    for (int m = 0; m < 4; ++m)
      av4[m] = *(const bf16x8*)&As[wr + m * 16 + lr][ko];
    #pragma unroll
    for (int n = 0; n < 4; ++n)
      bv4[n] = *(const bf16x8*)&Bs[wc + n * 16 + lr][ko];
    #pragma unroll
    for (int m = 0; m < 4; ++m)
      #pragma unroll
      for (int n = 0; n < 4; ++n)
        acc[m][n] = __builtin_amdgcn_mfma_f32_16x16x32_bf16(av4[m], bv4[n], acc[m][n], 0, 0, 0);
  }

  const int rq = lg * 4;
  #pragma unroll
  for (int m = 0; m < 4; ++m) {
    #pragma unroll
    for (int r = 0; r < 4; ++r) {
      int row = m0 + wr + m * 16 + rq + r;     // = b*2048 + s
      int bb = row >> 11, s = row & 2047;
      #pragma unroll
      for (int n = 0; n < 4; ++n) {
        int col = n0 + wc + n * 16 + lr;
        float val = acc[m][n][r] + bias[col];
        int hh = col >> 6, d = col & 63;
        if (z == 0) {
          // scale by 1/8 * log2(e): scores live in exp2 domain
          qh[((size_t)(bb * 16 + hh) * QLEN + s) * 64 + d] = f2b(val * 0.18033688f);
        } else if (z == 1) {
          kcat[(size_t)(bb * 4096 + 2048 + s) * 1024 + col] = val;
          kh[((size_t)(bb * 16 + hh) * KVTOT + 2048 + s) * 64 + d] = f2b(val);
        } else {
          vcat[(size_t)(bb * 4096 + 2048 + s) * 1024 + col] = val;
        }
      }
    }
  }
}

// ---------------------------------------------------------------------------
// Final GEMM: A bf16 (attn out), W bf16 — both via global_load_lds.
// ---------------------------------------------------------------------------
__global__ __launch_bounds__(256) void gemm_out(
    const u16* __restrict__ A, const u16* __restrict__ W,
    const float* __restrict__ bias, float* __restrict__ C) {
  const int K = 1024, N = 1024;
  __shared__ u16 As[128][32];
  __shared__ u16 Bs[128][32];
  const int t = threadIdx.x;
  const int m0 = blockIdx.y * 128, n0 = blockIdx.x * 128;
  const int lane = t & 63, wid = t >> 6;
  const int wr = (wid >> 1) * 64, wc = (wid & 1) * 64;
  const int lr = lane & 15, lg = lane >> 4;
  const int ko = lg * 8;

  f32x4 acc[4][4];
  #pragma unroll
  for (int m = 0; m < 4; ++m)
    #pragma unroll
    for (int n = 0; n < 4; ++n)
      acc[m][n] = (f32x4){0.f, 0.f, 0.f, 0.f};

  for (int k0 = 0; k0 < K; k0 += 32) {
    __syncthreads();
    #pragma unroll
    for (int j = 0; j < 2; ++j) {
      int idx = t + j * 256;
      int r = idx >> 2, c8 = (idx & 3) * 8;
      size_t ldsoff = (size_t)(j * 256 + (t & ~63)) * 8;
      gll16(A + (size_t)(m0 + r) * K + k0 + c8, &As[0][0] + ldsoff);
      gll16(W + (size_t)(n0 + r) * K + k0 + c8, &Bs[0][0] + ldsoff);
    }
    __syncthreads();
    bf16x8 av4[4], bv4[4];
    #pragma unroll
    for (int m = 0; m < 4; ++m)
      av4[m] = *(const bf16x8*)&As[wr + m * 16 + lr][ko];
    #pragma unroll
    for (int n = 0; n < 4; ++n)
      bv4[n] = *(const bf16x8*)&Bs[wc + n * 16 + lr][ko];
    #pragma unroll
    for (int m = 0; m < 4; ++m)
      #pragma unroll
      for (int n = 0; n < 4; ++n)
        acc[m][n] = __builtin_amdgcn_mfma_f32_16x16x32_bf16(av4[m], bv4[n], acc[m][n], 0, 0, 0);
  }

  const int rq = lg * 4;
  #pragma unroll
  for (int m = 0; m < 4; ++m) {
    #pragma unroll
    for (int r = 0; r < 4; ++r) {
      int row = m0 + wr + m * 16 + rq + r;
      float* cp = C + (size_t)row * N;
      #pragma unroll
      for (int n = 0; n < 4; ++n) {
        int col = n0 + wc + n * 16 + lr;
        cp[col] = acc[m][n][r] + bias[col];
      }
    }
  }
}

// ---------------------------------------------------------------------------
// vcat fp32 [B][4096][1024] -> bf16 transposed [B][16][64][4096]
// ---------------------------------------------------------------------------
__global__ __launch_bounds__(256) void repack_vt(
    const float* __restrict__ src, u16* __restrict__ dst) {
  __shared__ u16 T[64][72];
  const int t = threadIdx.x;
  const int kv0 = blockIdx.x * 64;
  const int bh = blockIdx.y;
  const int b = bh >> 4, h = bh & 15;
  #pragma unroll
  for (int it = 0; it < 4; ++it) {
    int idx = t + it * 256;
    int r = idx >> 4;
    int c4 = (idx & 15) * 4;
    float4 v = *(const float4*)(src + (size_t)(b * KVTOT + kv0 + r) * DMODEL + h * 64 + c4);
    *(uint2*)&T[r][c4] = make_uint2(cvt_pk_bf16(v.x, v.y), cvt_pk_bf16(v.z, v.w));
  }
  __syncthreads();
  #pragma unroll
  for (int it = 0; it < 2; ++it) {
    int idx = t + it * 256;
    int d = idx & 63;
    int kc8 = (idx >> 6) * 8;
    bf16x8 o;
    #pragma unroll
    for (int j = 0; j < 8; ++j) o[j] = (short)T[kc8 + j][d];
    *(bf16x8*)(dst + (size_t)((b * 16 + h) * 64 + d) * KVTOT + kv0 + kc8) = o;
  }
}

// ---------------------------------------------------------------------------
// MFMA flash attention v13 (= v10 + mask-only prefetch): flash-decode,
// 4 waves split KV (1024 each), K/V direct L2->regs, 4 q-frags, 2-stage
// pipeline, P double-buffered. Mask words double-buffered in regs (+8 VGPR);
// V loads unchanged (issued at iter top, ~4 stages of cover).
// ---------------------------------------------------------------------------
__global__ __launch_bounds__(256, 2) void attn_mfma(
    const u16* __restrict__ qh, const u16* __restrict__ kh,
    const u16* __restrict__ vt, const u64* __restrict__ mbits,
    u16* __restrict__ out) {
  // shm dual-role (barrier-separated):
  //  loop phase : per-wave P dbuf at shm + wid*2304  (2 x [16][72] u16)
  //  merge phase: bf16 O-partials    shm + w*4608    ([64][72] u16)
  __shared__ __align__(16) u16 shm[4 * 64 * 72];
  __shared__ float mM[4][64];
  __shared__ float mL[4][64];
  const int t = threadIdx.x;
  const int wid = t >> 6, lane = t & 63;
  const int lr = lane & 15, lg = lane >> 4;
  const int fid = blockIdx.x;                      // 0..1023
  const int virt = (fid & 7) * 128 + (fid >> 3);   // XCD-chunked: 4 bh per XCD
  const int bh = virt >> 5, qt = virt & 31;
  const int b = bh >> 4, h = bh & 15;
  const int q0 = qt * 64;

  u16* bufA = shm + wid * 2304;                    // wave-private [16][72]
  u16* bufB = bufA + 1152;

  bf16x8 ones;
  #pragma unroll
  for (int j = 0; j < 8; ++j) ones[j] = (short)0x3F80;

  // Q fragments (B-operand: col=q=lr, k=d=lg*8+j), 4 q-frags = 64 q rows
  bf16x8 qf[4][2];
  #pragma unroll
  for (int i = 0; i < 4; ++i) {
    const u16* qp = qh + ((size_t)bh * QLEN + q0 + i * 16 + lr) * 64 + lg * 8;
    qf[i][0] = *(const bf16x8*)qp;
    qf[i][1] = *(const bf16x8*)(qp + 32);
  }

  // this wave's private kv window: [wid*1024, wid*1024+1024)
  const u16* kbase = kh + (size_t)bh * KVTOT * 64 + (size_t)wid * 1024 * 64;
  const u16* vbase = vt + (size_t)bh * 64 * KVTOT + wid * 1024;
  const u64* mbase = mbits + ((size_t)b * QLEN + q0 + lr) * 64 + wid * 16;

  float mprev[4] = {SENT2, SENT2, SENT2, SENT2};
  f32x4 oacc[4][4];
  f32x4 oaccL[4];
  #pragma unroll
  for (int i = 0; i < 4; ++i) {
    oaccL[i] = (f32x4){0.f, 0.f, 0.f, 0.f};
    #pragma unroll
    for (int dt = 0; dt < 4; ++dt) oacc[i][dt] = (f32x4){0.f, 0.f, 0.f, 0.f};
  }

  // preload K fragments for tile 0 (A-operand: row=kv=tile*16+lr, k=d)
  bf16x8 kf[4][2];
  #pragma unroll
  for (int tile = 0; tile < 4; ++tile) {
    const u16* kp = kbase + (size_t)(tile * 16 + lr) * 64 + lg * 8;
    kf[tile][0] = *(const bf16x8*)kp;
    kf[tile][1] = *(const bf16x8*)(kp + 32);
  }

  bf16x8 vf[4][2];

  // ---- pipeline stages (i is a literal at every call site -> constant-folds)
  auto QK = [&](int i, f32x4* sacc, u64 mb) {
    u64 mq = mb >> (lg * 4);
    const float negm = -mprev[i], negmm = MASKC2 - mprev[i];
    #pragma unroll
    for (int tile = 0; tile < 4; ++tile) {
      unsigned nib = (unsigned)((mq >> (tile * 16)) & 0xFull);
      #pragma unroll
      for (int r = 0; r < 4; ++r)
        sacc[tile][r] = (nib & (1u << r)) ? negmm : negm;
    }
    __builtin_amdgcn_s_setprio(1);
    #pragma unroll
    for (int tile = 0; tile < 4; ++tile) {
      sacc[tile] = __builtin_amdgcn_mfma_f32_16x16x32_bf16(kf[tile][0], qf[i][0], sacc[tile], 0, 0, 0);
      sacc[tile] = __builtin_amdgcn_mfma_f32_16x16x32_bf16(kf[tile][1], qf[i][1], sacc[tile], 0, 0, 0);
    }
    __builtin_amdgcn_s_setprio(0);
  };

  auto SM = [&](int i, f32x4* sacc, u16* pbuf) {
    // per-lane local max; __all over 64 lanes covers the whole 16q x 64kv tile
    float t1 = max3f(sacc[0][0], sacc[0][1], sacc[0][2]);
    float t2 = max3f(sacc[0][3], sacc[1][0], sacc[1][1]);
    float t3 = max3f(sacc[1][2], sacc[1][3], sacc[2][0]);
    float t4 = max3f(sacc[2][1], sacc[2][2], sacc[2][3]);
    float t5 = max3f(sacc[3][0], sacc[3][1], sacc[3][2]);
    float lmax = fmaxf(sacc[3][3], t1);
    lmax = max3f(lmax, t2, t3);
    lmax = max3f(lmax, t4, t5);
    if (!__all(lmax <= 11.0f)) {         // rare: rescale path
      float rmax = fmaxf(lmax, __shfl_xor(lmax, 16));
      rmax = fmaxf(rmax, __shfl_xor(rmax, 32));
      float shift = fmaxf(rmax, 0.f);
      float corr = exp2v(-shift);
      float cr[4];
      #pragma unroll
      for (int r = 0; r < 4; ++r) cr[r] = __shfl(corr, lg * 4 + r);
      #pragma unroll
      for (int dt = 0; dt < 4; ++dt)
        #pragma unroll
        for (int r = 0; r < 4; ++r) oacc[i][dt][r] *= cr[r];
      #pragma unroll
      for (int r = 0; r < 4; ++r) oaccL[i][r] *= cr[r];
      mprev[i] += shift;
      #pragma unroll
      for (int tile = 0; tile < 4; ++tile)
        #pragma unroll
        for (int r = 0; r < 4; ++r) sacc[tile][r] -= shift;
    }
    #pragma unroll
    for (int tile = 0; tile < 4; ++tile) {
      float p0 = exp2v(sacc[tile][0]);
      float p1 = exp2v(sacc[tile][1]);
      float p2 = exp2v(sacc[tile][2]);
      float p3 = exp2v(sacc[tile][3]);
      *(uint2*)&pbuf[lr * 72 + tile * 16 + lg * 4] =
          make_uint2(cvt_pk_bf16(p0, p1), cvt_pk_bf16(p2, p3));
    }
  };

  auto PV = [&](int i, const u16* pbuf) {
    bf16x8 pa0 = *(const bf16x8*)&pbuf[lr * 72 + lg * 8];
    bf16x8 pa1 = *(const bf16x8*)&pbuf[lr * 72 + 32 + lg * 8];
    __builtin_amdgcn_s_setprio(1);
    #pragma unroll
    for (int dt = 0; dt < 4; ++dt) {
      oacc[i][dt] = __builtin_amdgcn_mfma_f32_16x16x32_bf16(pa0, vf[dt][0], oacc[i][dt], 0, 0, 0);
      oacc[i][dt] = __builtin_amdgcn_mfma_f32_16x16x32_bf16(pa1, vf[dt][1], oacc[i][dt], 0, 0, 0);
    }
    oaccL[i] = __builtin_amdgcn_mfma_f32_16x16x32_bf16(pa0, ones, oaccL[i], 0, 0, 0);
    oaccL[i] = __builtin_amdgcn_mfma_f32_16x16x32_bf16(pa1, ones, oaccL[i], 0, 0, 0);
    __builtin_amdgcn_s_setprio(0);
  };

  f32x4 sA[4], sB[4];

  // mask double buffer (register resident, rotated by macro) — iter 0 preload
  u64 mb0[4], mb1[4];
  #pragma unroll
  for (int i = 0; i < 4; ++i) mb0[i] = mbase[(size_t)i * 1024];

#define ITER_M(IT, MCUR, MNXT)                                                 \
  {                                                                            \
    const int it_ = (IT);                                                      \
    /* V fragments for this tile (B-operand), as in v10 */                     \
    const u16* vp_ = vbase + it_ * 64;                                         \
    _Pragma("unroll")                                                          \
    for (int dt = 0; dt < 4; ++dt) {                                           \
      const u16* vq_ = vp_ + (size_t)(dt * 16 + lr) * KVTOT + lg * 8;          \
      vf[dt][0] = *(const bf16x8*)vq_;                                         \
      vf[dt][1] = *(const bf16x8*)(vq_ + 32);                                  \
    }                                                                          \
    /* prefetch NEXT iter's mask words (full iteration of cover) */            \
    if (it_ + 1 < 16) {                                                        \
      _Pragma("unroll")                                                        \
      for (int i = 0; i < 4; ++i) MNXT[i] = mbase[(size_t)i * 1024 + it_ + 1]; \
    }                                                                          \
    QK(0, sA, MCUR[0]);                                                        \
    SM(0, sA, bufA);                                                           \
    QK(1, sB, MCUR[1]);                                                        \
    PV(0, bufA);                                                               \
    SM(1, sB, bufB);                                                           \
    QK(2, sA, MCUR[2]);                                                        \
    PV(1, bufB);                                                               \
    SM(2, sA, bufA);                                                           \
    QK(3, sB, MCUR[3]);                                                        \
    if (it_ + 1 < 16) {                                                        \
      const u16* kp_ = kbase + (size_t)(it_ + 1) * 4096;                       \
      _Pragma("unroll")                                                        \
      for (int tile = 0; tile < 4; ++tile) {                                   \
        const u16* kq_ = kp_ + (size_t)(tile * 16 + lr) * 64 + lg * 8;         \
        kf[tile][0] = *(const bf16x8*)kq_;                                     \
        kf[tile][1] = *(const bf16x8*)(kq_ + 32);                              \
      }                                                                        \
    }                                                                          \
    PV(2, bufA);                                                               \
    SM(3, sB, bufB);                                                           \
    PV(3, bufB);                                                               \
  }

  for (int ii = 0; ii < 8; ++ii) {
    ITER_M(2 * ii,     mb0, mb1);
    ITER_M(2 * ii + 1, mb1, mb0);
  }
#undef ITER_M

  // ---- merge the 4 kv-partials; staging overlays P buffers -> barrier first
  __syncthreads();
  u16* mo = shm + wid * 4608;                      // [64][72] bf16
  #pragma unroll
  for (int i = 0; i < 4; ++i)
    #pragma unroll
    for (int dt = 0; dt < 4; ++dt)
      #pragma unroll
      for (int r = 0; r < 4; ++r)
        mo[(i * 16 + lg * 4 + r) * 72 + dt * 16 + lr] = f2b(oacc[i][dt][r]);
  if (lr == 0) {
    #pragma unroll
    for (int i = 0; i < 4; ++i)
      #pragma unroll
      for (int r = 0; r < 4; ++r)
        mL[wid][i * 16 + lg * 4 + r] = oaccL[i][r];
  }
  if (lg == 0) {
    #pragma unroll
    for (int i = 0; i < 4; ++i) mM[wid][i * 16 + lr] = mprev[i];
  }
  __syncthreads();

  // wave `wid` merges q-rows [wid*16, wid*16+16); lane: q=lr, d=lg*16..+15
  const int q = wid * 16 + lr;
  float m0 = mM[0][q], m1 = mM[1][q], m2 = mM[2][q], m3 = mM[3][q];
  float mm = fmaxf(max3f(m0, m1, m2), m3);
  float w0 = exp2v(m0 - mm), w1 = exp2v(m1 - mm);
  float w2 = exp2v(m2 - mm), w3 = exp2v(m3 - mm);
  float l = mL[0][q] * w0 + mL[1][q] * w1 + mL[2][q] * w2 + mL[3][q] * w3;
  float inv = 1.f / l;
  float wgt[4] = {w0 * inv, w1 * inv, w2 * inv, w3 * inv};
  float o[16];
  #pragma unroll
  for (int j = 0; j < 16; ++j) o[j] = 0.f;
  #pragma unroll
  for (int w = 0; w < 4; ++w) {
    const u16* src = shm + w * 4608 + q * 72 + lg * 16;
    bf16x8 a0 = *(const bf16x8*)src;
    bf16x8 a1 = *(const bf16x8*)(src + 8);
    #pragma unroll
    for (int j = 0; j < 8; ++j) {
      o[j]     += b2f((u16)a0[j]) * wgt[w];
      o[8 + j] += b2f((u16)a1[j]) * wgt[w];
    }
  }
  u16* op = out + ((size_t)b * QLEN + q0 + q) * DMODEL + h * 64 + lg * 16;
  uint4 wA = {cvt_pk_bf16(o[0], o[1]), cvt_pk_bf16(o[2], o[3]),
              cvt_pk_bf16(o[4], o[5]), cvt_pk_bf16(o[6], o[7])};
  uint4 wB = {cvt_pk_bf16(o[8], o[9]), cvt_pk_bf16(o[10], o[11]),
              cvt_pk_bf16(o[12], o[13]), cvt_pk_bf16(o[14], o[15])};
  *(uint4*)op = wA;
  *(uint4*)(op + 8) = wB;
}

// ---------------------------------------------------------------------------
extern "C" void kernel_launch(void* const* d_in, const int* in_sizes, int n_in,
                              void* d_out, int out_size, void* d_ws, size_t ws_size,
                              hipStream_t stream) {
  const float* q      = (const float*)d_in[0];
  const float* k      = (const float*)d_in[1];
  const float* v      = (const float*)d_in[2];
  const float* past_k = (const float*)d_in[3];
  const float* past_v = (const float*)d_in[4];
  const int*   mask   = (const int*)d_in[5];
  const float* Wq     = (const float*)d_in[6];
  const float* bq     = (const float*)d_in[7];
  const float* Wk     = (const float*)d_in[8];
  const float* bk     = (const float*)d_in[9];
  const float* Wv     = (const float*)d_in[10];
  const float* bv     = (const float*)d_in[11];
  const float* Wl     = (const float*)d_in[12];
  const float* bl     = (const float*)d_in[13];

  float* xout = (float*)d_out;                    // (B, Q, D)
  float* kcat = xout + 4194304;                   // (B, 4096, D)
  float* vcat = xout + 12582912;

  // ws (u16 units): attno 0..4M | qh 4..8M | kh 8..16M | vt 16..24M |
  //                 Wb 24..28M | mbits after (2MB)
  // ab bf16 activations OVERLAY [attno | vt] (consumed before those are written)
  u16* wsb = (u16*)d_ws;
  u16* attno = wsb;
  u16* qh = wsb + 4194304;
  u16* kh = wsb + 8388608;
  u16* vt = wsb + 16777216;
  u16* Wb = wsb + 25165824;
  u64* mbits = (u64*)(wsb + 29360128);

  maskpack<<<65536, 256, 0, stream>>>(mask, mbits);
  prep<<<12288, 256, 0, stream>>>(past_k, past_v, kcat, vcat, kh,
                                  Wq, Wk, Wv, Wl, Wb,
                                  q, k, v, attno, vt);

  gemm_qkv<<<dim3(8, 32, 3), 256, 0, stream>>>(
      attno, vt, Wb, bq, bk, bv, qh, kcat, kh, vcat);

  repack_vt<<<dim3(64, 32), 256, 0, stream>>>(vcat, vt);

  attn_mfma<<<1024, 256, 0, stream>>>(qh, kh, vt, mbits, attno);

  gemm_out<<<dim3(8, 32), 256, 0, stream>>>(attno, Wb + 3145728, bl, xout);
}

// Round 14
// 287.396 us; speedup vs baseline: 1.2417x; 1.0280x over previous
//
#include <hip/hip_runtime.h>

#define QLEN 2048
#define KVTOT 4096
#define DMODEL 1024
// log2(e)-domain constants: scores are pre-scaled by 0.125*log2(e)
#define MASKC2 -14427.0f   // -10000 * log2(e)
#define SENT2  -28854.0f

typedef __attribute__((ext_vector_type(8))) short bf16x8;
typedef __attribute__((ext_vector_type(4))) float f32x4;
typedef unsigned short u16;
typedef unsigned int u32;
typedef unsigned long long u64;

__device__ __forceinline__ u16 f2b(float f) {
  union { float f; unsigned u; } v; v.f = f;
  unsigned r = v.u + 0x7FFFu + ((v.u >> 16) & 1u);
  return (u16)(r >> 16);
}

__device__ __forceinline__ float b2f(u16 x) {
  union { u32 u; float f; } v; v.u = (u32)x << 16; return v.f;
}

__device__ __forceinline__ u32 cvt_pk_bf16(float lo, float hi) {
  u32 r;
  asm("v_cvt_pk_bf16_f32 %0, %1, %2" : "=v"(r) : "v"(lo), "v"(hi));
  return r;
}

__device__ __forceinline__ float exp2v(float x) {
  float r;
  asm("v_exp_f32 %0, %1" : "=v"(r) : "v"(x));
  return r;
}

__device__ __forceinline__ float max3f(float a, float b, float c) {
  float r;
  asm("v_max3_f32 %0, %1, %2, %3" : "=v"(r) : "v"(a), "v"(b), "v"(c));
  return r;
}

// async global->LDS, 16B per lane; lds dest = wave-uniform base + lane*16
__device__ __forceinline__ void gll16(const u16* g, u16* l) {
  __builtin_amdgcn_global_load_lds(
      (const __attribute__((address_space(1))) u32*)g,
      (__attribute__((address_space(3))) u32*)l, 16, 0, 0);
}

// ---------------------------------------------------------------------------
// Fused elementwise prep (one dispatch, blockIdx ranges):
//  [0,4096)          : past_k/past_v -> k_cat/v_cat + kh bf16
//  [4096,6144)       : weights fp32 -> bf16 (4 matrices)
//  [6144,12288)      : activations q/k/v fp32 -> bf16
//  [12288,77824)     : mask int32 -> u64 bitpack
// ---------------------------------------------------------------------------
__global__ __launch_bounds__(256) void prep(
    const float* __restrict__ pk, const float* __restrict__ pv,
    float* __restrict__ kcat, float* __restrict__ vcat,
    u16* __restrict__ kh,
    const float* __restrict__ w0, const float* __restrict__ w1,
    const float* __restrict__ w2, const float* __restrict__ w3,
    u16* __restrict__ wdst,
    const float* __restrict__ aq, const float* __restrict__ ak,
    const float* __restrict__ av, u16* __restrict__ adst0,
    u16* __restrict__ adst12,
    const int* __restrict__ mask, u64* __restrict__ bits) {
  const int bid = blockIdx.x;
  if (bid < 4096) {
    int i = bid * 256 + threadIdx.x;             // float4 units
    int b = i >> 19;
    int r = i & 524287;
    size_t src = (size_t)i * 4;
    size_t dst = ((size_t)b * 1048576 + r) * 4;
    float4 kk = *(const float4*)&pk[src];
    float4 vv = *(const float4*)&pv[src];
    *(float4*)&kcat[dst] = kk;
    *(float4*)&vcat[dst] = vv;
    int s = r >> 8;
    int c4 = (r & 255) * 4;
    int h = c4 >> 6, d = c4 & 63;
    uint2 w = make_uint2(cvt_pk_bf16(kk.x, kk.y), cvt_pk_bf16(kk.z, kk.w));
    *(uint2*)&kh[((size_t)(b * 16 + h) * KVTOT + s) * 64 + d] = w;
  } else if (bid < 6144) {
    int t2 = bid - 4096;
    int y = t2 >> 9, x = t2 & 511;
    const float* src = y == 0 ? w0 : y == 1 ? w1 : y == 2 ? w2 : w3;
    size_t i = ((size_t)x * 256 + threadIdx.x) * 8;
    float4 a = *(const float4*)&src[i];
    float4 b = *(const float4*)&src[i + 4];
    uint4 o = {cvt_pk_bf16(a.x, a.y), cvt_pk_bf16(a.z, a.w),
               cvt_pk_bf16(b.x, b.y), cvt_pk_bf16(b.z, b.w)};
    *(uint4*)&wdst[(size_t)y * 1048576 + i] = o;
  } else if (bid < 12288) {
    int t3 = bid - 6144;
    int y = t3 >> 11, x = t3 & 2047;
    const float* src = y == 0 ? aq : y == 1 ? ak : av;
    u16* dst = y == 0 ? adst0 : adst12 + (size_t)(y - 1) * 4194304;
    size_t i = ((size_t)x * 256 + threadIdx.x) * 8;
    float4 a = *(const float4*)&src[i];
    float4 b = *(const float4*)&src[i + 4];
    uint4 o = {cvt_pk_bf16(a.x, a.y), cvt_pk_bf16(a.z, a.w),
               cvt_pk_bf16(b.x, b.y), cvt_pk_bf16(b.z, b.w)};
    *(uint4*)&dst[i] = o;
  } else {
    int t4 = bid - 12288;                        // 0..65535
    int w = t4 * 4 + (threadIdx.x >> 6);
    int lane = threadIdx.x & 63;
    int mv = mask[(size_t)w * 64 + lane];
    u64 b = __ballot(mv != 0);
    if (lane == 0) bits[w] = b;
  }
}

// ---------------------------------------------------------------------------
// z-fused QKV projections: C = A*W^T + bias. BOTH sides bf16 via
// global_load_lds. grid (8,32,3). A: z==0 -> Ab0, z>=1 -> Ab12+(z-1)*4M.
// ---------------------------------------------------------------------------
__global__ __launch_bounds__(256) void gemm_qkv(
    const u16* __restrict__ Ab0, const u16* __restrict__ Ab12,
    const u16* __restrict__ Wb,
    const float* __restrict__ bq, const float* __restrict__ bk,
    const float* __restrict__ bv,
    u16* __restrict__ qh, float* __restrict__ kcat, u16* __restrict__ kh,
    float* __restrict__ vcat) {
  const int K = 1024, N = 1024;
  __shared__ u16 As[128][32];
  __shared__ u16 Bs[128][32];
  const int z = blockIdx.z;
  const u16* A = (z == 0) ? Ab0 : Ab12 + (size_t)(z - 1) * 4194304;
  const u16* W = Wb + (size_t)z * 1048576;
  const float* bias = (z == 0) ? bq : (z == 1) ? bk : bv;
  const int t = threadIdx.x;
  const int m0 = blockIdx.y * 128, n0 = blockIdx.x * 128;
  const int lane = t & 63, wid = t >> 6;
  const int wr = (wid >> 1) * 64, wc = (wid & 1) * 64;
  const int lr = lane & 15, lg = lane >> 4;
  const int ko = lg * 8;

  f32x4 acc[4][4];
  #pragma unroll
  for (int m = 0; m < 4; ++m)
    #pragma unroll
    for (int n = 0; n < 4; ++n)
      acc[m][n] = (f32x4){0.f, 0.f, 0.f, 0.f};

  for (int k0 = 0; k0 < K; k0 += 32) {
    __syncthreads();
    #pragma unroll
    for (int j = 0; j < 2; ++j) {
      int idx = t + j * 256;
      int r = idx >> 2, c8 = (idx & 3) * 8;
      size_t ldsoff = (size_t)(j * 256 + (t & ~63)) * 8;
      gll16(A + (size_t)(m0 + r) * K + k0 + c8, &As[0][0] + ldsoff);
      gll16(W + (size_t)(n0 + r) * K + k0 + c8, &Bs[0][0] + ldsoff);
    }
    __syncthreads();
    bf16x8 av4[4], bv4[4];
    #pragma unroll
    for (int m = 0; m < 4; ++m)
      av4[m] = *(const bf16x8*)&As[wr + m * 16 + lr][ko];
    #pragma unroll
    for (int n = 0; n < 4; ++n)
      bv4[n] = *(const bf16x8*)&Bs[wc + n * 16 + lr][ko];
    #pragma unroll
    for (int m = 0; m < 4; ++m)
      #pragma unroll
      for (int n = 0; n < 4; ++n)
        acc[m][n] = __builtin_amdgcn_mfma_f32_16x16x32_bf16(av4[m], bv4[n], acc[m][n], 0, 0, 0);
  }

  const int rq = lg * 4;
  #pragma unroll
  for (int m = 0; m < 4; ++m) {
    #pragma unroll
    for (int r = 0; r < 4; ++r) {
      int row = m0 + wr + m * 16 + rq + r;     // = b*2048 + s
      int bb = row >> 11, s = row & 2047;
      #pragma unroll
      for (int n = 0; n < 4; ++n) {
        int col = n0 + wc + n * 16 + lr;
        float val = acc[m][n][r] + bias[col];
        int hh = col >> 6, d = col & 63;
        if (z == 0) {
          // scale by 1/8 * log2(e): scores live in exp2 domain
          qh[((size_t)(bb * 16 + hh) * QLEN + s) * 64 + d] = f2b(val * 0.18033688f);
        } else if (z == 1) {
          kcat[(size_t)(bb * 4096 + 2048 + s) * 1024 + col] = val;
          kh[((size_t)(bb * 16 + hh) * KVTOT + 2048 + s) * 64 + d] = f2b(val);
        } else {
          vcat[(size_t)(bb * 4096 + 2048 + s) * 1024 + col] = val;
        }
      }
    }
  }
}

// ---------------------------------------------------------------------------
// Final GEMM: A bf16 (attn out), W bf16, both global_load_lds.
// 64x128 tile -> 512 blocks = 2 blocks/CU (barrier drains overlap).
// ---------------------------------------------------------------------------
__global__ __launch_bounds__(256) void gemm_out(
    const u16* __restrict__ A, const u16* __restrict__ W,
    const float* __restrict__ bias, float* __restrict__ C) {
  const int K = 1024, N = 1024;
  __shared__ u16 As[64][32];
  __shared__ u16 Bs[128][32];
  const int t = threadIdx.x;
  const int m0 = blockIdx.y * 64, n0 = blockIdx.x * 128;
  const int lane = t & 63, wid = t >> 6;
  const int wr = (wid >> 1) * 32, wc = (wid & 1) * 64;   // 2x2 waves, 32x64 each
  const int lr = lane & 15, lg = lane >> 4;
  const int ko = lg * 8;

  f32x4 acc[2][4];
  #pragma unroll
  for (int m = 0; m < 2; ++m)
    #pragma unroll
    for (int n = 0; n < 4; ++n)
      acc[m][n] = (f32x4){0.f, 0.f, 0.f, 0.f};

  for (int k0 = 0; k0 < K; k0 += 32) {
    __syncthreads();
    {
      // A tile: 64x32 = 4KB = 256 lanes x 16B (1 gll16 each)
      int r = t >> 2, c8 = (t & 3) * 8;
      gll16(A + (size_t)(m0 + r) * K + k0 + c8, &As[0][0] + (size_t)(t & ~63) * 8);
    }
    #pragma unroll
    for (int j = 0; j < 2; ++j) {
      // B tile: 128x32 = 8KB = 2 gll16 per lane
      int idx = t + j * 256;
      int r = idx >> 2, c8 = (idx & 3) * 8;
      gll16(W + (size_t)(n0 + r) * K + k0 + c8,
            &Bs[0][0] + (size_t)(j * 256 + (t & ~63)) * 8);
    }
    __syncthreads();
    bf16x8 av4[2], bv4[4];
    #pragma unroll
    for (int m = 0; m < 2; ++m)
      av4[m] = *(const bf16x8*)&As[wr + m * 16 + lr][ko];
    #pragma unroll
    for (int n = 0; n < 4; ++n)
      bv4[n] = *(const bf16x8*)&Bs[wc + n * 16 + lr][ko];
    #pragma unroll
    for (int m = 0; m < 2; ++m)
      #pragma unroll
      for (int n = 0; n < 4; ++n)
        acc[m][n] = __builtin_amdgcn_mfma_f32_16x16x32_bf16(av4[m], bv4[n], acc[m][n], 0, 0, 0);
  }

  const int rq = lg * 4;
  #pragma unroll
  for (int m = 0; m < 2; ++m) {
    #pragma unroll
    for (int r = 0; r < 4; ++r) {
      int row = m0 + wr + m * 16 + rq + r;
      float* cp = C + (size_t)row * N;
      #pragma unroll
      for (int n = 0; n < 4; ++n) {
        int col = n0 + wc + n * 16 + lr;
        cp[col] = acc[m][n][r] + bias[col];
      }
    }
  }
}

// ---------------------------------------------------------------------------
// vcat fp32 [B][4096][1024] -> bf16 transposed [B][16][64][4096]
// ---------------------------------------------------------------------------
__global__ __launch_bounds__(256) void repack_vt(
    const float* __restrict__ src, u16* __restrict__ dst) {
  __shared__ u16 T[64][72];
  const int t = threadIdx.x;
  const int kv0 = blockIdx.x * 64;
  const int bh = blockIdx.y;
  const int b = bh >> 4, h = bh & 15;
  #pragma unroll
  for (int it = 0; it < 4; ++it) {
    int idx = t + it * 256;
    int r = idx >> 4;
    int c4 = (idx & 15) * 4;
    float4 v = *(const float4*)(src + (size_t)(b * KVTOT + kv0 + r) * DMODEL + h * 64 + c4);
    *(uint2*)&T[r][c4] = make_uint2(cvt_pk_bf16(v.x, v.y), cvt_pk_bf16(v.z, v.w));
  }
  __syncthreads();
  #pragma unroll
  for (int it = 0; it < 2; ++it) {
    int idx = t + it * 256;
    int d = idx & 63;
    int kc8 = (idx >> 6) * 8;
    bf16x8 o;
    #pragma unroll
    for (int j = 0; j < 8; ++j) o[j] = (short)T[kc8 + j][d];
    *(bf16x8*)(dst + (size_t)((b * 16 + h) * 64 + d) * KVTOT + kv0 + kc8) = o;
  }
}

// ---------------------------------------------------------------------------
// MFMA flash attention v13 (plateau config): flash-decode, 4 waves split KV
// (1024 each), K/V direct L2->regs, 4 q-frags, 2-stage pipeline, P dbuf in
// LDS, mask words double-buffered in regs.
// ---------------------------------------------------------------------------
__global__ __launch_bounds__(256, 2) void attn_mfma(
    const u16* __restrict__ qh, const u16* __restrict__ kh,
    const u16* __restrict__ vt, const u64* __restrict__ mbits,
    u16* __restrict__ out) {
  // shm dual-role (barrier-separated):
  //  loop phase : per-wave P dbuf at shm + wid*2304  (2 x [16][72] u16)
  //  merge phase: bf16 O-partials    shm + w*4608    ([64][72] u16)
  __shared__ __align__(16) u16 shm[4 * 64 * 72];
  __shared__ float mM[4][64];
  __shared__ float mL[4][64];
  const int t = threadIdx.x;
  const int wid = t >> 6, lane = t & 63;
  const int lr = lane & 15, lg = lane >> 4;
  const int fid = blockIdx.x;                      // 0..1023
  const int virt = (fid & 7) * 128 + (fid >> 3);   // XCD-chunked: 4 bh per XCD
  const int bh = virt >> 5, qt = virt & 31;
  const int b = bh >> 4, h = bh & 15;
  const int q0 = qt * 64;

  u16* bufA = shm + wid * 2304;                    // wave-private [16][72]
  u16* bufB = bufA + 1152;

  bf16x8 ones;
  #pragma unroll
  for (int j = 0; j < 8; ++j) ones[j] = (short)0x3F80;

  // Q fragments (B-operand: col=q=lr, k=d=lg*8+j), 4 q-frags = 64 q rows
  bf16x8 qf[4][2];
  #pragma unroll
  for (int i = 0; i < 4; ++i) {
    const u16* qp = qh + ((size_t)bh * QLEN + q0 + i * 16 + lr) * 64 + lg * 8;
    qf[i][0] = *(const bf16x8*)qp;
    qf[i][1] = *(const bf16x8*)(qp + 32);
  }

  // this wave's private kv window: [wid*1024, wid*1024+1024)
  const u16* kbase = kh + (size_t)bh * KVTOT * 64 + (size_t)wid * 1024 * 64;
  const u16* vbase = vt + (size_t)bh * 64 * KVTOT + wid * 1024;
  const u64* mbase = mbits + ((size_t)b * QLEN + q0 + lr) * 64 + wid * 16;

  float mprev[4] = {SENT2, SENT2, SENT2, SENT2};
  f32x4 oacc[4][4];
  f32x4 oaccL[4];
  #pragma unroll
  for (int i = 0; i < 4; ++i) {
    oaccL[i] = (f32x4){0.f, 0.f, 0.f, 0.f};
    #pragma unroll
    for (int dt = 0; dt < 4; ++dt) oacc[i][dt] = (f32x4){0.f, 0.f, 0.f, 0.f};
  }

  // preload K fragments for tile 0 (A-operand: row=kv=tile*16+lr, k=d)
  bf16x8 kf[4][2];
  #pragma unroll
  for (int tile = 0; tile < 4; ++tile) {
    const u16* kp = kbase + (size_t)(tile * 16 + lr) * 64 + lg * 8;
    kf[tile][0] = *(const bf16x8*)kp;
    kf[tile][1] = *(const bf16x8*)(kp + 32);
  }

  bf16x8 vf[4][2];

  // ---- pipeline stages (i is a literal at every call site -> constant-folds)
  auto QK = [&](int i, f32x4* sacc, u64 mb) {
    u64 mq = mb >> (lg * 4);
    const float negm = -mprev[i], negmm = MASKC2 - mprev[i];
    #pragma unroll
    for (int tile = 0; tile < 4; ++tile) {
      unsigned nib = (unsigned)((mq >> (tile * 16)) & 0xFull);
      #pragma unroll
      for (int r = 0; r < 4; ++r)
        sacc[tile][r] = (nib & (1u << r)) ? negmm : negm;
    }
    __builtin_amdgcn_s_setprio(1);
    #pragma unroll
    for (int tile = 0; tile < 4; ++tile) {
      sacc[tile] = __builtin_amdgcn_mfma_f32_16x16x32_bf16(kf[tile][0], qf[i][0], sacc[tile], 0, 0, 0);
      sacc[tile] = __builtin_amdgcn_mfma_f32_16x16x32_bf16(kf[tile][1], qf[i][1], sacc[tile], 0, 0, 0);
    }
    __builtin_amdgcn_s_setprio(0);
  };

  auto SM = [&](int i, f32x4* sacc, u16* pbuf) {
    // per-lane local max; __all over 64 lanes covers the whole 16q x 64kv tile
    float t1 = max3f(sacc[0][0], sacc[0][1], sacc[0][2]);
    float t2 = max3f(sacc[0][3], sacc[1][0], sacc[1][1]);
    float t3 = max3f(sacc[1][2], sacc[1][3], sacc[2][0]);
    float t4 = max3f(sacc[2][1], sacc[2][2], sacc[2][3]);
    float t5 = max3f(sacc[3][0], sacc[3][1], sacc[3][2]);
    float lmax = fmaxf(sacc[3][3], t1);
    lmax = max3f(lmax, t2, t3);
    lmax = max3f(lmax, t4, t5);
    if (!__all(lmax <= 11.0f)) {         // rare: rescale path
      float rmax = fmaxf(lmax, __shfl_xor(lmax, 16));
      rmax = fmaxf(rmax, __shfl_xor(rmax, 32));
      float shift = fmaxf(rmax, 0.f);
      float corr = exp2v(-shift);
      float cr[4];
      #pragma unroll
      for (int r = 0; r < 4; ++r) cr[r] = __shfl(corr, lg * 4 + r);
      #pragma unroll
      for (int dt = 0; dt < 4; ++dt)
        #pragma unroll
        for (int r = 0; r < 4; ++r) oacc[i][dt][r] *= cr[r];
      #pragma unroll
      for (int r = 0; r < 4; ++r) oaccL[i][r] *= cr[r];
      mprev[i] += shift;
      #pragma unroll
      for (int tile = 0; tile < 4; ++tile)
        #pragma unroll
        for (int r = 0; r < 4; ++r) sacc[tile][r] -= shift;
    }
    #pragma unroll
    for (int tile = 0; tile < 4; ++tile) {
      float p0 = exp2v(sacc[tile][0]);
      float p1 = exp2v(sacc[tile][1]);
      float p2 = exp2v(sacc[tile][2]);
      float p3 = exp2v(sacc[tile][3]);
      *(uint2*)&pbuf[lr * 72 + tile * 16 + lg * 4] =
          make_uint2(cvt_pk_bf16(p0, p1), cvt_pk_bf16(p2, p3));
    }
  };

  auto PV = [&](int i, const u16* pbuf) {
    bf16x8 pa0 = *(const bf16x8*)&pbuf[lr * 72 + lg * 8];
    bf16x8 pa1 = *(const bf16x8*)&pbuf[lr * 72 + 32 + lg * 8];
    __builtin_amdgcn_s_setprio(1);
    #pragma unroll
    for (int dt = 0; dt < 4; ++dt) {
      oacc[i][dt] = __builtin_amdgcn_mfma_f32_16x16x32_bf16(pa0, vf[dt][0], oacc[i][dt], 0, 0, 0);
      oacc[i][dt] = __builtin_amdgcn_mfma_f32_16x16x32_bf16(pa1, vf[dt][1], oacc[i][dt], 0, 0, 0);
    }
    oaccL[i] = __builtin_amdgcn_mfma_f32_16x16x32_bf16(pa0, ones, oaccL[i], 0, 0, 0);
    oaccL[i] = __builtin_amdgcn_mfma_f32_16x16x32_bf16(pa1, ones, oaccL[i], 0, 0, 0);
    __builtin_amdgcn_s_setprio(0);
  };

  f32x4 sA[4], sB[4];

  // mask double buffer (register resident, rotated by macro) — iter 0 preload
  u64 mb0[4], mb1[4];
  #pragma unroll
  for (int i = 0; i < 4; ++i) mb0[i] = mbase[(size_t)i * 1024];

#define ITER_M(IT, MCUR, MNXT)                                                 \
  {                                                                            \
    const int it_ = (IT);                                                      \
    /* V fragments for this tile (B-operand) */                                \
    const u16* vp_ = vbase + it_ * 64;                                         \
    _Pragma("unroll")                                                          \
    for (int dt = 0; dt < 4; ++dt) {                                           \
      const u16* vq_ = vp_ + (size_t)(dt * 16 + lr) * KVTOT + lg * 8;          \
      vf[dt][0] = *(const bf16x8*)vq_;                                         \
      vf[dt][1] = *(const bf16x8*)(vq_ + 32);                                  \
    }                                                                          \
    /* prefetch NEXT iter's mask words (full iteration of cover) */            \
    if (it_ + 1 < 16) {                                                        \
      _Pragma("unroll")                                                        \
      for (int i = 0; i < 4; ++i) MNXT[i] = mbase[(size_t)i * 1024 + it_ + 1]; \
    }                                                                          \
    QK(0, sA, MCUR[0]);                                                        \
    SM(0, sA, bufA);                                                           \
    QK(1, sB, MCUR[1]);                                                        \
    PV(0, bufA);                                                               \
    SM(1, sB, bufB);                                                           \
    QK(2, sA, MCUR[2]);                                                        \
    PV(1, bufB);                                                               \
    SM(2, sA, bufA);                                                           \
    QK(3, sB, MCUR[3]);                                                        \
    if (it_ + 1 < 16) {                                                        \
      const u16* kp_ = kbase + (size_t)(it_ + 1) * 4096;                       \
      _Pragma("unroll")                                                        \
      for (int tile = 0; tile < 4; ++tile) {                                   \
        const u16* kq_ = kp_ + (size_t)(tile * 16 + lr) * 64 + lg * 8;         \
        kf[tile][0] = *(const bf16x8*)kq_;                                     \
        kf[tile][1] = *(const bf16x8*)(kq_ + 32);                              \
      }                                                                        \
    }                                                                          \
    PV(2, bufA);                                                               \
    SM(3, sB, bufB);                                                           \
    PV(3, bufB);                                                               \
  }

  for (int ii = 0; ii < 8; ++ii) {
    ITER_M(2 * ii,     mb0, mb1);
    ITER_M(2 * ii + 1, mb1, mb0);
  }
#undef ITER_M

  // ---- merge the 4 kv-partials; staging overlays P buffers -> barrier first
  __syncthreads();
  u16* mo = shm + wid * 4608;                      // [64][72] bf16
  #pragma unroll
  for (int i = 0; i < 4; ++i)
    #pragma unroll
    for (int dt = 0; dt < 4; ++dt)
      #pragma unroll
      for (int r = 0; r < 4; ++r)
        mo[(i * 16 + lg * 4 + r) * 72 + dt * 16 + lr] = f2b(oacc[i][dt][r]);
  if (lr == 0) {
    #pragma unroll
    for (int i = 0; i < 4; ++i)
      #pragma unroll
      for (int r = 0; r < 4; ++r)
        mL[wid][i * 16 + lg * 4 + r] = oaccL[i][r];
  }
  if (lg == 0) {
    #pragma unroll
    for (int i = 0; i < 4; ++i) mM[wid][i * 16 + lr] = mprev[i];
  }
  __syncthreads();

  // wave `wid` merges q-rows [wid*16, wid*16+16); lane: q=lr, d=lg*16..+15
  const int q = wid * 16 + lr;
  float m0 = mM[0][q], m1 = mM[1][q], m2 = mM[2][q], m3 = mM[3][q];
  float mm = fmaxf(max3f(m0, m1, m2), m3);
  float w0 = exp2v(m0 - mm), w1 = exp2v(m1 - mm);
  float w2 = exp2v(m2 - mm), w3 = exp2v(m3 - mm);
  float l = mL[0][q] * w0 + mL[1][q] * w1 + mL[2][q] * w2 + mL[3][q] * w3;
  float inv = 1.f / l;
  float wgt[4] = {w0 * inv, w1 * inv, w2 * inv, w3 * inv};
  float o[16];
  #pragma unroll
  for (int j = 0; j < 16; ++j) o[j] = 0.f;
  #pragma unroll
  for (int w = 0; w < 4; ++w) {
    const u16* src = shm + w * 4608 + q * 72 + lg * 16;
    bf16x8 a0 = *(const bf16x8*)src;
    bf16x8 a1 = *(const bf16x8*)(src + 8);
    #pragma unroll
    for (int j = 0; j < 8; ++j) {
      o[j]     += b2f((u16)a0[j]) * wgt[w];
      o[8 + j] += b2f((u16)a1[j]) * wgt[w];
    }
  }
  u16* op = out + ((size_t)b * QLEN + q0 + q) * DMODEL + h * 64 + lg * 16;
  uint4 wA = {cvt_pk_bf16(o[0], o[1]), cvt_pk_bf16(o[2], o[3]),
              cvt_pk_bf16(o[4], o[5]), cvt_pk_bf16(o[6], o[7])};
  uint4 wB = {cvt_pk_bf16(o[8], o[9]), cvt_pk_bf16(o[10], o[11]),
              cvt_pk_bf16(o[12], o[13]), cvt_pk_bf16(o[14], o[15])};
  *(uint4*)op = wA;
  *(uint4*)(op + 8) = wB;
}

// ---------------------------------------------------------------------------
extern "C" void kernel_launch(void* const* d_in, const int* in_sizes, int n_in,
                              void* d_out, int out_size, void* d_ws, size_t ws_size,
                              hipStream_t stream) {
  const float* q      = (const float*)d_in[0];
  const float* k      = (const float*)d_in[1];
  const float* v      = (const float*)d_in[2];
  const float* past_k = (const float*)d_in[3];
  const float* past_v = (const float*)d_in[4];
  const int*   mask   = (const int*)d_in[5];
  const float* Wq     = (const float*)d_in[6];
  const float* bq     = (const float*)d_in[7];
  const float* Wk     = (const float*)d_in[8];
  const float* bk     = (const float*)d_in[9];
  const float* Wv     = (const float*)d_in[10];
  const float* bv     = (const float*)d_in[11];
  const float* Wl     = (const float*)d_in[12];
  const float* bl     = (const float*)d_in[13];

  float* xout = (float*)d_out;                    // (B, Q, D)
  float* kcat = xout + 4194304;                   // (B, 4096, D)
  float* vcat = xout + 12582912;

  // ws (u16 units): attno 0..4M | qh 4..8M | kh 8..16M | vt 16..24M |
  //                 Wb 24..28M | mbits after (2MB)
  // ab bf16 activations OVERLAY [attno | vt] (consumed before those are written)
  u16* wsb = (u16*)d_ws;
  u16* attno = wsb;
  u16* qh = wsb + 4194304;
  u16* kh = wsb + 8388608;
  u16* vt = wsb + 16777216;
  u16* Wb = wsb + 25165824;
  u64* mbits = (u64*)(wsb + 29360128);

  prep<<<77824, 256, 0, stream>>>(past_k, past_v, kcat, vcat, kh,
                                  Wq, Wk, Wv, Wl, Wb,
                                  q, k, v, attno, vt,
                                  mask, mbits);

  gemm_qkv<<<dim3(8, 32, 3), 256, 0, stream>>>(
      attno, vt, Wb, bq, bk, bv, qh, kcat, kh, vcat);

  repack_vt<<<dim3(64, 32), 256, 0, stream>>>(vcat, vt);

  attn_mfma<<<1024, 256, 0, stream>>>(qh, kh, vt, mbits, attno);

  gemm_out<<<dim3(8, 64), 256, 0, stream>>>(attno, Wb + 3145728, bl, xout);
}